// Round 2
// baseline (4366.587 us; speedup 1.0000x reference)
//
#include <hip/hip_runtime.h>

// ResidualVectorQuantizer: N=131072, DIM=128, LEVELS=3, K=1024, BETA=0.25, USAGE_REG=1e-3
// Outputs (flat fp32 in d_out): quantized [N*128] | codes [N*3] | commit | usage
//
// Numerics contract with the np fp32 reference:
//  - m = x·W_k must be BIT-EXACT vs BLAS sgemm: strict sequential FMA chain over
//    k=0..127, single accumulator, acc0 = fl(a0*b0). (GPU fmaf == CPU vfmadd.)
//  - d = (S - 2*m) + w via __fsub_rn/__fmul_rn/__fadd_rn (NO fma contraction).
//    Since S is on its own ulp-grid, d_k = S + D_k with D_k independent of S:
//    S's summation order cannot affect argmin or softmax. m's bits are the only
//    discriminator at quantization boundaries.
//  - residual chain (x - q0) - q1 elementwise fp32 => bit-exact vs reference.
//  - argmin: ascending scan, strict < => first occurrence on ties.
//  - loss accumulations in f64, final scalar combine in fp32 per ref order.

#define NROWS   131072
#define DIMS    128
#define KCODES  1024
#define NLEV    3

#define QF_OFF   ((size_t)NROWS * DIMS)          // 16777216
#define CODE_OFF QF_OFF
#define SCAL_OFF (QF_OFF + (size_t)NROWS * 3)    // 17170432

// ---------------- ws layout ----------------
// avgp   : 3*1024 doubles @ 0        (24576 B)
// commit : 3 doubles      @ 24576
// wk     : 3*1024 floats  @ 24704

__global__ __launch_bounds__(256) void init_acc(double* acc) {
    for (int i = threadIdx.x; i < 3075; i += 256) acc[i] = 0.0;
}

__global__ __launch_bounds__(256) void wnorm_kernel(const float* __restrict__ W,
                                                    float* __restrict__ wk) {
    const int wave = threadIdx.x >> 6, lane = threadIdx.x & 63;
    const int c = blockIdx.x * 4 + wave;          // 0..3071 (level*1024 + k)
    const float2 v = *(const float2*)(W + (size_t)c * DIMS + 2 * lane);
    float s = v.x * v.x + v.y * v.y;
#pragma unroll
    for (int m = 32; m >= 1; m >>= 1) s += __shfl_xor(s, m, 64);
    if (lane == 0) wk[c] = s;
}

__global__ __launch_bounds__(256) void rvq_level(
    const float* __restrict__ x, const float* __restrict__ W,
    const float* __restrict__ wk, float* __restrict__ out,
    double* __restrict__ avgp, double* __restrict__ commit, const int level) {

    __shared__ float  rowT[DIMS][16];     // residual rows, k-major (matmul operand)
    __shared__ float  rowR[16][132];      // residual rows, row-major (+pad) for epilogue
    __shared__ float  wT[DIMS][DIMS];     // W chunk, k-major, f4-XOR-swizzled columns
    __shared__ float  dbuf[16][KCODES];   // d, then exp(dmin-d)
    __shared__ float  Srow[16];
    __shared__ float  redf[16][17];
    __shared__ float  redv[16][16];
    __shared__ int    redi[16][16];
    __shared__ float  rowmin[16];
    __shared__ int    rowidx[16];
    __shared__ double redl[16][16];
    __shared__ float  Lf[16];
    __shared__ double redc[256];

    const int t = threadIdx.x;
    const int base = blockIdx.x * 16;
    const float* codesF = out + CODE_OFF;
    const float* Wl  = W  + (size_t)level * KCODES * DIMS;
    const float* wkl = wk + level * KCODES;

    // ---- phase 0: load rows, recompute residual from previous codes (bit-exact) ----
    {
        const int r = t >> 4, i = t & 15;
        const size_t n = base + r;
        float4 v0 = *(const float4*)(x + n * DIMS + i * 8);
        float4 v1 = *(const float4*)(x + n * DIMS + i * 8 + 4);
        for (int j = 0; j < level; ++j) {
            const int idx = (int)codesF[n * 3 + j];
            const float* q = W + ((size_t)(j * KCODES + idx)) * DIMS + i * 8;
            const float4 q0 = *(const float4*)q;
            const float4 q1 = *(const float4*)(q + 4);
            v0.x = __fsub_rn(v0.x, q0.x); v0.y = __fsub_rn(v0.y, q0.y);
            v0.z = __fsub_rn(v0.z, q0.z); v0.w = __fsub_rn(v0.w, q0.w);
            v1.x = __fsub_rn(v1.x, q1.x); v1.y = __fsub_rn(v1.y, q1.y);
            v1.z = __fsub_rn(v1.z, q1.z); v1.w = __fsub_rn(v1.w, q1.w);
        }
        *(float4*)&rowR[r][i * 8]     = v0;
        *(float4*)&rowR[r][i * 8 + 4] = v1;
        rowT[i * 8 + 0][r] = v0.x; rowT[i * 8 + 1][r] = v0.y;
        rowT[i * 8 + 2][r] = v0.z; rowT[i * 8 + 3][r] = v0.w;
        rowT[i * 8 + 4][r] = v1.x; rowT[i * 8 + 5][r] = v1.y;
        rowT[i * 8 + 6][r] = v1.z; rowT[i * 8 + 7][r] = v1.w;
        float sq = v0.x * v0.x + v0.y * v0.y + v0.z * v0.z + v0.w * v0.w
                 + v1.x * v1.x + v1.y * v1.y + v1.z * v1.z + v1.w * v1.w;
        redf[r][i] = sq;
    }
    __syncthreads();
    if (t < 16) {
        float s = 0.f;
        for (int i = 0; i < 16; ++i) s += redf[t][i];
        Srow[t] = s;   // per-row shift of S is argmin/probs-invariant (on-grid)
    }
    __syncthreads();

    const int rt = t >> 5, ct = t & 31;
    const float S0 = Srow[2 * rt], S1 = Srow[2 * rt + 1];

    // ---- phase 1: d = (S - 2*m) + w for all 1024 codes, 8 chunks of 128 ----
    for (int cc = 0; cc < 8; ++cc) {
        const int cbase = cc * 128;
        // stage W chunk -> wT (k-major, f4 XOR swizzle for conflict-free reads)
#pragma unroll
        for (int i = 0; i < 16; ++i) {
            const int fid = t + 256 * i;
            const int c = fid >> 5, kg = fid & 31;
            const float4 wv = *(const float4*)(Wl + (size_t)(cbase + c) * DIMS + 4 * kg);
            const int col = 4 * ((c >> 2) ^ kg) + (c & 3);
            wT[4 * kg + 0][col] = wv.x;
            wT[4 * kg + 1][col] = wv.y;
            wT[4 * kg + 2][col] = wv.z;
            wT[4 * kg + 3][col] = wv.w;
        }
        __syncthreads();

        // Single accumulator per (row,code), STRICT k-ascending fmaf chain:
        // bit-exact replica of the BLAS sgemm microkernel accumulation.
        float a[2][4] = {};
        for (int kb = 0; kb < DIMS; kb += 4) {
            const int key = kb >> 2;
#pragma unroll
            for (int kk = 0; kk < 4; ++kk) {
                const int k = kb + kk;
                const float2 rp = *(const float2*)&rowT[k][2 * rt];
                const float4 wv = *(const float4*)&wT[k][4 * (ct ^ key)];
                a[0][0] = fmaf(rp.x, wv.x, a[0][0]);
                a[0][1] = fmaf(rp.x, wv.y, a[0][1]);
                a[0][2] = fmaf(rp.x, wv.z, a[0][2]);
                a[0][3] = fmaf(rp.x, wv.w, a[0][3]);
                a[1][0] = fmaf(rp.y, wv.x, a[1][0]);
                a[1][1] = fmaf(rp.y, wv.y, a[1][1]);
                a[1][2] = fmaf(rp.y, wv.z, a[1][2]);
                a[1][3] = fmaf(rp.y, wv.w, a[1][3]);
            }
        }
        const float4 wkv = *(const float4*)(wkl + cbase + 4 * ct);
#pragma unroll
        for (int i = 0; i < 2; ++i) {
            const float Si = (i == 0) ? S0 : S1;
            float4 dv;   // MUST NOT contract: reproduces reference fp32 quantization
            dv.x = __fadd_rn(__fsub_rn(Si, __fmul_rn(2.0f, a[i][0])), wkv.x);
            dv.y = __fadd_rn(__fsub_rn(Si, __fmul_rn(2.0f, a[i][1])), wkv.y);
            dv.z = __fadd_rn(__fsub_rn(Si, __fmul_rn(2.0f, a[i][2])), wkv.z);
            dv.w = __fadd_rn(__fsub_rn(Si, __fmul_rn(2.0f, a[i][3])), wkv.w);
            *(float4*)&dbuf[2 * rt + i][cbase + 4 * ct] = dv;
        }
        __syncthreads();
    }

    // ---- phase 2: per-row argmin, first-occurrence tie-break ----
    {
        const int r = t >> 4, j = t & 15;
        float best = 3.4e38f; int bi = 0;
        for (int s4 = 0; s4 < 64; s4 += 4) {
            const float4 dv = *(const float4*)&dbuf[r][j * 64 + s4];
            if (dv.x < best) { best = dv.x; bi = j * 64 + s4; }
            if (dv.y < best) { best = dv.y; bi = j * 64 + s4 + 1; }
            if (dv.z < best) { best = dv.z; bi = j * 64 + s4 + 2; }
            if (dv.w < best) { best = dv.w; bi = j * 64 + s4 + 3; }
        }
        redv[r][j] = best; redi[r][j] = bi;
    }
    __syncthreads();
    if (t < 16) {
        float best = redv[t][0]; int bi = redi[t][0];
        for (int j = 1; j < 16; ++j) {
            const float v = redv[t][j];
            if (v < best) { best = v; bi = redi[t][j]; }  // ascending j => first kept
        }
        rowmin[t] = best; rowidx[t] = bi;
    }
    __syncthreads();

    // ---- phase 3: e = exp(dmin - d) in place, L = sum(e) in f64 ----
    {
        const int r = t >> 4, j = t & 15;
        const float mn = rowmin[r];
        double ls = 0.0;
        for (int s4 = 0; s4 < 64; s4 += 4) {
            float4 dv = *(const float4*)&dbuf[r][j * 64 + s4];
            float4 ev;
            ev.x = expf(__fsub_rn(mn, dv.x));
            ev.y = expf(__fsub_rn(mn, dv.y));
            ev.z = expf(__fsub_rn(mn, dv.z));
            ev.w = expf(__fsub_rn(mn, dv.w));
            *(float4*)&dbuf[r][j * 64 + s4] = ev;
            ls += (double)ev.x + (double)ev.y + (double)ev.z + (double)ev.w;
        }
        redl[r][j] = ls;
    }
    __syncthreads();
    if (t < 16) {
        double L = 0.0;
        for (int j = 0; j < 16; ++j) L += redl[t][j];
        Lf[t] = (float)L;
    }
    __syncthreads();

    // ---- phase 4: avg_probs partial sums (probs = e / L, fp32 divide like ref) ----
#pragma unroll
    for (int q = 0; q < 4; ++q) {
        const int k = t + 256 * q;
        float s = 0.f;
        for (int r = 0; r < 16; ++r)
            s = __fadd_rn(s, __fdiv_rn(dbuf[r][k], Lf[r]));
        atomicAdd(&avgp[level * KCODES + k], (double)s);
    }

    // ---- phase 5: commit loss partial + codes output ----
    {
        const int r = t >> 4, i = t & 15;
        const size_t n = base + r;
        const int idx = rowidx[r];
        const float* qp = Wl + (size_t)idx * DIMS + i * 8;
        const float4 q0 = *(const float4*)qp;
        const float4 q1 = *(const float4*)(qp + 4);
        const float4 v0 = *(const float4*)&rowR[r][i * 8];
        const float4 v1 = *(const float4*)&rowR[r][i * 8 + 4];
        double cs = 0.0; float rn;
        rn = __fsub_rn(v0.x, q0.x); cs += (double)rn * (double)rn;
        rn = __fsub_rn(v0.y, q0.y); cs += (double)rn * (double)rn;
        rn = __fsub_rn(v0.z, q0.z); cs += (double)rn * (double)rn;
        rn = __fsub_rn(v0.w, q0.w); cs += (double)rn * (double)rn;
        rn = __fsub_rn(v1.x, q1.x); cs += (double)rn * (double)rn;
        rn = __fsub_rn(v1.y, q1.y); cs += (double)rn * (double)rn;
        rn = __fsub_rn(v1.z, q1.z); cs += (double)rn * (double)rn;
        rn = __fsub_rn(v1.w, q1.w); cs += (double)rn * (double)rn;
        redc[t] = cs;
        if (i == 0) out[CODE_OFF + n * 3 + level] = (float)idx;
    }
    __syncthreads();
    for (int off = 128; off >= 1; off >>= 1) {
        if (t < off) redc[t] += redc[t + off];
        __syncthreads();
    }
    if (t == 0) atomicAdd(&commit[level], redc[0]);
}

__global__ __launch_bounds__(256) void finalize_kernel(const double* __restrict__ avgp,
                                                       const double* __restrict__ commit,
                                                       float* __restrict__ out) {
    __shared__ double red[256];
    __shared__ float  kls[3];
    const int t = threadIdx.x;
    for (int l = 0; l < 3; ++l) {
        double p = 0.0;
        for (int k = t; k < KCODES; k += 256) {
            const float avg = (float)(avgp[l * KCODES + k] * (1.0 / 131072.0));
            p += (double)avg * log((double)avg * 1024.0 + 1e-8);
        }
        red[t] = p; __syncthreads();
        for (int off = 128; off >= 1; off >>= 1) {
            if (t < off) red[t] += red[t + off];
            __syncthreads();
        }
        if (t == 0) kls[l] = (float)red[0];
        __syncthreads();
    }
    if (t == 0) {
        float c = 0.f, u = 0.f;
        for (int l = 0; l < 3; ++l) {
            const float m = (float)(commit[l] * (1.0 / 16777216.0));
            c = __fadd_rn(c, m);                       // + mean((sg(r)-q)^2)
            c = __fadd_rn(c, __fmul_rn(0.25f, m));     // + BETA * mean((r-sg(q))^2)
            u = __fadd_rn(u, __fmul_rn(1e-3f, kls[l]));
        }
        out[SCAL_OFF]     = c;
        out[SCAL_OFF + 1] = u;
    }
}

__global__ __launch_bounds__(256) void gather_kernel(const float* __restrict__ W,
                                                     float* __restrict__ out) {
    const size_t g = (size_t)blockIdx.x * 256 + threadIdx.x;   // f4 index
    const size_t n = g >> 5;
    const int f = (int)(g & 31);
    const float* codes = out + CODE_OFF + n * 3;
    const int c0 = (int)codes[0], c1 = (int)codes[1], c2 = (int)codes[2];
    const float4 a = *(const float4*)(W + (size_t)c0 * DIMS + 4 * f);
    const float4 b = *(const float4*)(W + (size_t)(KCODES + c1) * DIMS + 4 * f);
    const float4 c = *(const float4*)(W + (size_t)(2 * KCODES + c2) * DIMS + 4 * f);
    float4 o;   // ((q1 + q2) + q3), fp32 like reference
    o.x = __fadd_rn(__fadd_rn(a.x, b.x), c.x);
    o.y = __fadd_rn(__fadd_rn(a.y, b.y), c.y);
    o.z = __fadd_rn(__fadd_rn(a.z, b.z), c.z);
    o.w = __fadd_rn(__fadd_rn(a.w, b.w), c.w);
    *(float4*)(out + n * DIMS + 4 * f) = o;
}

extern "C" void kernel_launch(void* const* d_in, const int* in_sizes, int n_in,
                              void* d_out, int out_size, void* d_ws, size_t ws_size,
                              hipStream_t stream) {
    const float* x = (const float*)d_in[0];
    const float* W = (const float*)d_in[1];
    float* out = (float*)d_out;
    double* avgp   = (double*)d_ws;
    double* commit = (double*)((char*)d_ws + 24576);
    float*  wk     = (float*)((char*)d_ws + 24704);

    hipLaunchKernelGGL(init_acc, dim3(1), dim3(256), 0, stream, avgp);
    hipLaunchKernelGGL(wnorm_kernel, dim3(768), dim3(256), 0, stream, W, wk);
    for (int l = 0; l < NLEV; ++l)
        hipLaunchKernelGGL(rvq_level, dim3(NROWS / 16), dim3(256), 0, stream,
                           x, W, wk, out, avgp, commit, l);
    hipLaunchKernelGGL(finalize_kernel, dim3(1), dim3(256), 0, stream, avgp, commit, out);
    hipLaunchKernelGGL(gather_kernel, dim3((NROWS * 32) / 256), dim3(256), 0, stream, W, out);
}

// Round 3
// 3561.883 us; speedup vs baseline: 1.2259x; 1.2259x over previous
//
#include <hip/hip_runtime.h>

// ResidualVectorQuantizer: N=131072, DIM=128, LEVELS=3, K=1024, BETA=0.25, USAGE_REG=1e-3
// Outputs (flat fp32 in d_out): quantized [N*128] | codes [N*3] | commit | usage
//
// Numerics contract with the np fp32 reference (validated in round 2 — do not change):
//  - m = x·W_k: strict sequential fmaf chain over k=0..127, single accumulator.
//  - d = (S - 2*m) + w via __fsub_rn/__fmul_rn/__fadd_rn (no contraction).
//  - argmin: first occurrence on ties (lexicographic (value, index) min).
//  - residual chain (x - q0) - q1 elementwise fp32, recomputed from codes per level.
//  - losses: tolerance is loose (~2%); commit uses d at argmin (== ||r-q||^2 to ~1e-5
//    rel), avg_probs accumulate fp32, KL in f64.
//
// Performance structure (round 3): W pre-transposed to k-major so the hot loop's
// weight operand streams from L2 via coalesced global float4 loads (VMEM pipe);
// rows live in 8.4 KB LDS read as wave-uniform ds_read_b128 broadcasts; d/argmin/
// softmax entirely in registers + shuffles. 64 accumulators/thread, ~10.5 KB LDS,
// launch_bounds(256,3) -> 3 blocks/CU (vs round 2: 155 KB LDS, 1 block/CU, LDS-bound).

#define NROWS   131072
#define DIMS    128
#define KCODES  1024
#define NLEV    3

#define QF_OFF   ((size_t)NROWS * DIMS)          // 16777216
#define CODE_OFF QF_OFF
#define SCAL_OFF (QF_OFF + (size_t)NROWS * 3)    // 17170432

// ---------------- ws layout ----------------
// avgp   : 3*1024 floats  @ 0        (12288 B)
// commit : 3 doubles      @ 12288    (24 B)
// wk     : 3*1024 floats  @ 12320    (12288 B)
// WT     : 3*128*1024 fl  @ 24608    (1572864 B)  k-major codebooks
#define WS_COMMIT_OFF 12288
#define WS_WK_OFF     12320
#define WS_WT_OFF     24608

__global__ __launch_bounds__(256) void init_acc(float* avgp, double* commit) {
    for (int i = threadIdx.x; i < 3072; i += 256) avgp[i] = 0.0f;
    if (threadIdx.x < 3) commit[threadIdx.x] = 0.0;
}

__global__ __launch_bounds__(256) void wnorm_kernel(const float* __restrict__ W,
                                                    float* __restrict__ wk) {
    const int wave = threadIdx.x >> 6, lane = threadIdx.x & 63;
    const int c = blockIdx.x * 4 + wave;          // 0..3071 (level*1024 + k)
    const float2 v = *(const float2*)(W + (size_t)c * DIMS + 2 * lane);
    float s = v.x * v.x + v.y * v.y;
#pragma unroll
    for (int m = 32; m >= 1; m >>= 1) s += __shfl_xor(s, m, 64);
    if (lane == 0) wk[c] = s;
}

// WT[l][k][c] = W[l][c][k]
__global__ __launch_bounds__(256) void transpose_w(const float* __restrict__ W,
                                                   float* __restrict__ WT) {
    __shared__ float tile[32][65];
    const int l = blockIdx.z, k0 = blockIdx.y * 32, c0 = blockIdx.x * 64;
    const float* Wl = W + (size_t)l * KCODES * DIMS;
    float* WTl = WT + (size_t)l * DIMS * KCODES;
    {
        const int ci = threadIdx.x >> 2;            // 0..63
        const int kg = (threadIdx.x & 3) * 8;       // 0,8,16,24
        const float4 a = *(const float4*)(Wl + (size_t)(c0 + ci) * DIMS + k0 + kg);
        const float4 b = *(const float4*)(Wl + (size_t)(c0 + ci) * DIMS + k0 + kg + 4);
        tile[kg + 0][ci] = a.x; tile[kg + 1][ci] = a.y;
        tile[kg + 2][ci] = a.z; tile[kg + 3][ci] = a.w;
        tile[kg + 4][ci] = b.x; tile[kg + 5][ci] = b.y;
        tile[kg + 6][ci] = b.z; tile[kg + 7][ci] = b.w;
    }
    __syncthreads();
    {
        const int k = threadIdx.x >> 3;             // 0..31
        const int cg = (threadIdx.x & 7) * 8;       // 0..56
        float4 o0, o1;
        o0.x = tile[k][cg + 0]; o0.y = tile[k][cg + 1];
        o0.z = tile[k][cg + 2]; o0.w = tile[k][cg + 3];
        o1.x = tile[k][cg + 4]; o1.y = tile[k][cg + 5];
        o1.z = tile[k][cg + 6]; o1.w = tile[k][cg + 7];
        *(float4*)(WTl + (size_t)(k0 + k) * KCODES + c0 + cg)     = o0;
        *(float4*)(WTl + (size_t)(k0 + k) * KCODES + c0 + cg + 4) = o1;
    }
}

__global__ __launch_bounds__(256, 3) void rvq_level(
    const float* __restrict__ x, const float* __restrict__ W,
    const float* __restrict__ WT, const float* __restrict__ wk,
    float* __restrict__ out, float* __restrict__ avgp,
    double* __restrict__ commit, const int level) {

    __shared__ float rowR[16][132];   // residual rows, row-major (+pad; bcast-read)
    __shared__ float redf[16][17];
    __shared__ float Srow[16];
    __shared__ float wminv[16][4];    // per-wave (row) argmin partials
    __shared__ int   wmini[16][4];
    __shared__ float rowmin[16];
    __shared__ int   rowidx[16];
    __shared__ float wsum[16][4];
    __shared__ float rcpL[16];

    const int t = threadIdx.x;
    const int wave = t >> 6, lane = t & 63;
    const int c = wave * 256 + lane * 4;          // this thread's 4 codes
    const size_t base = (size_t)blockIdx.x * 16;
    const float* codesF = out + CODE_OFF;
    const float* WTl = WT + (size_t)level * DIMS * KCODES;
    const float* wkl = wk + level * KCODES;

    // ---- phase 0: stage 16 residual rows into LDS (bit-exact chain from codes) ----
    {
        const int r = t >> 4, i = t & 15;
        const size_t n = base + r;
        float4 v0 = *(const float4*)(x + n * DIMS + i * 8);
        float4 v1 = *(const float4*)(x + n * DIMS + i * 8 + 4);
        for (int j = 0; j < level; ++j) {
            const int idx = (int)codesF[n * 3 + j];
            const float* q = W + ((size_t)(j * KCODES + idx)) * DIMS + i * 8;
            const float4 q0 = *(const float4*)q;
            const float4 q1 = *(const float4*)(q + 4);
            v0.x = __fsub_rn(v0.x, q0.x); v0.y = __fsub_rn(v0.y, q0.y);
            v0.z = __fsub_rn(v0.z, q0.z); v0.w = __fsub_rn(v0.w, q0.w);
            v1.x = __fsub_rn(v1.x, q1.x); v1.y = __fsub_rn(v1.y, q1.y);
            v1.z = __fsub_rn(v1.z, q1.z); v1.w = __fsub_rn(v1.w, q1.w);
        }
        *(float4*)&rowR[r][i * 8]     = v0;
        *(float4*)&rowR[r][i * 8 + 4] = v1;
        float sq = v0.x * v0.x + v0.y * v0.y + v0.z * v0.z + v0.w * v0.w
                 + v1.x * v1.x + v1.y * v1.y + v1.z * v1.z + v1.w * v1.w;
        redf[r][i] = sq;
    }
    __syncthreads();
    if (t < 16) {
        float s = 0.f;
        for (int i = 0; i < 16; ++i) s += redf[t][i];
        Srow[t] = s;   // on-grid shift: order can't affect argmin/softmax
    }
    __syncthreads();

    // ---- phase 1: acc[r][j] = row_r · W_{c+j}, strict k-ascending fmaf chains ----
    float acc[16][4] = {};
#pragma unroll 1
    for (int kt = 0; kt < 16; ++kt) {
        float wv[8][4];   // W^T[k][c..c+3] for k = kt*8 .. kt*8+7 (coalesced, L2-hot)
#pragma unroll
        for (int kk = 0; kk < 8; ++kk)
            *(float4*)&wv[kk][0] = *(const float4*)(WTl + (size_t)(kt * 8 + kk) * KCODES + c);
#pragma unroll
        for (int r = 0; r < 16; ++r) {
            const float4 ra = *(const float4*)&rowR[r][kt * 8];      // uniform bcast
            const float4 rb = *(const float4*)&rowR[r][kt * 8 + 4];  // uniform bcast
            float* A = acc[r];
            A[0] = fmaf(ra.x, wv[0][0], A[0]); A[1] = fmaf(ra.x, wv[0][1], A[1]);
            A[2] = fmaf(ra.x, wv[0][2], A[2]); A[3] = fmaf(ra.x, wv[0][3], A[3]);
            A[0] = fmaf(ra.y, wv[1][0], A[0]); A[1] = fmaf(ra.y, wv[1][1], A[1]);
            A[2] = fmaf(ra.y, wv[1][2], A[2]); A[3] = fmaf(ra.y, wv[1][3], A[3]);
            A[0] = fmaf(ra.z, wv[2][0], A[0]); A[1] = fmaf(ra.z, wv[2][1], A[1]);
            A[2] = fmaf(ra.z, wv[2][2], A[2]); A[3] = fmaf(ra.z, wv[2][3], A[3]);
            A[0] = fmaf(ra.w, wv[3][0], A[0]); A[1] = fmaf(ra.w, wv[3][1], A[1]);
            A[2] = fmaf(ra.w, wv[3][2], A[2]); A[3] = fmaf(ra.w, wv[3][3], A[3]);
            A[0] = fmaf(rb.x, wv[4][0], A[0]); A[1] = fmaf(rb.x, wv[4][1], A[1]);
            A[2] = fmaf(rb.x, wv[4][2], A[2]); A[3] = fmaf(rb.x, wv[4][3], A[3]);
            A[0] = fmaf(rb.y, wv[5][0], A[0]); A[1] = fmaf(rb.y, wv[5][1], A[1]);
            A[2] = fmaf(rb.y, wv[5][2], A[2]); A[3] = fmaf(rb.y, wv[5][3], A[3]);
            A[0] = fmaf(rb.z, wv[6][0], A[0]); A[1] = fmaf(rb.z, wv[6][1], A[1]);
            A[2] = fmaf(rb.z, wv[6][2], A[2]); A[3] = fmaf(rb.z, wv[6][3], A[3]);
            A[0] = fmaf(rb.w, wv[7][0], A[0]); A[1] = fmaf(rb.w, wv[7][1], A[1]);
            A[2] = fmaf(rb.w, wv[7][2], A[2]); A[3] = fmaf(rb.w, wv[7][3], A[3]);
        }
    }

    // ---- phase 2: d in place, per-row argmin via lexicographic shuffle reduce ----
    const float4 wkv = *(const float4*)(wkl + c);
#pragma unroll
    for (int r = 0; r < 16; ++r) {
        const float Sr = Srow[r];
        float d0 = __fadd_rn(__fsub_rn(Sr, __fmul_rn(2.0f, acc[r][0])), wkv.x);
        float d1 = __fadd_rn(__fsub_rn(Sr, __fmul_rn(2.0f, acc[r][1])), wkv.y);
        float d2 = __fadd_rn(__fsub_rn(Sr, __fmul_rn(2.0f, acc[r][2])), wkv.z);
        float d3 = __fadd_rn(__fsub_rn(Sr, __fmul_rn(2.0f, acc[r][3])), wkv.w);
        acc[r][0] = d0; acc[r][1] = d1; acc[r][2] = d2; acc[r][3] = d3;
        float v = d0; int bi = c;
        if (d1 < v) { v = d1; bi = c + 1; }
        if (d2 < v) { v = d2; bi = c + 2; }
        if (d3 < v) { v = d3; bi = c + 3; }
#pragma unroll
        for (int m = 1; m < 64; m <<= 1) {
            const float vo = __shfl_xor(v, m, 64);
            const int   io = __shfl_xor(bi, m, 64);
            if (vo < v || (vo == v && io < bi)) { v = vo; bi = io; }
        }
        if (lane == 0) { wminv[r][wave] = v; wmini[r][wave] = bi; }
    }
    __syncthreads();
    if (t < 16) {
        float v = wminv[t][0]; int bi = wmini[t][0];
        for (int w = 1; w < 4; ++w) {
            const float vo = wminv[t][w]; const int io = wmini[t][w];
            if (vo < v || (vo == v && io < bi)) { v = vo; bi = io; }
        }
        rowmin[t] = v; rowidx[t] = bi;
        out[CODE_OFF + (base + t) * 3 + level] = (float)bi;
    }
    __syncthreads();

    // ---- phase 3: e = exp(dmin - d) in place, row sums via shuffle ----
#pragma unroll
    for (int r = 0; r < 16; ++r) {
        const float mn = rowmin[r];
        float e0 = expf(__fsub_rn(mn, acc[r][0]));
        float e1 = expf(__fsub_rn(mn, acc[r][1]));
        float e2 = expf(__fsub_rn(mn, acc[r][2]));
        float e3 = expf(__fsub_rn(mn, acc[r][3]));
        acc[r][0] = e0; acc[r][1] = e1; acc[r][2] = e2; acc[r][3] = e3;
        float s = (e0 + e1) + (e2 + e3);
#pragma unroll
        for (int m = 1; m < 64; m <<= 1) s += __shfl_xor(s, m, 64);
        if (lane == 0) wsum[r][wave] = s;
    }
    __syncthreads();
    if (t < 16) {
        const float L = (wsum[t][0] + wsum[t][1]) + (wsum[t][2] + wsum[t][3]);
        rcpL[t] = 1.0f / L;
    }
    if (t == 64) {   // commit partial: d at argmin == ||r - q||^2 (loss tolerance loose)
        double cs = 0.0;
        for (int r = 0; r < 16; ++r) cs += (double)rowmin[r];
        atomicAdd(&commit[level], cs);
    }
    __syncthreads();

    // ---- phase 4: avg_probs partials (fp32 atomics, one per code per block) ----
#pragma unroll
    for (int j = 0; j < 4; ++j) {
        float s = 0.f;
#pragma unroll
        for (int r = 0; r < 16; ++r) s = fmaf(acc[r][j], rcpL[r], s);
        atomicAdd(&avgp[level * KCODES + c + j], s);
    }
}

__global__ __launch_bounds__(256) void finalize_kernel(const float* __restrict__ avgp,
                                                       const double* __restrict__ commit,
                                                       float* __restrict__ out) {
    __shared__ double red[256];
    __shared__ float  kls[3];
    const int t = threadIdx.x;
    for (int l = 0; l < 3; ++l) {
        double p = 0.0;
        for (int k = t; k < KCODES; k += 256) {
            const float avg = avgp[l * KCODES + k] * (1.0f / 131072.0f);
            p += (double)avg * log((double)avg * 1024.0 + 1e-8);
        }
        red[t] = p; __syncthreads();
        for (int off = 128; off >= 1; off >>= 1) {
            if (t < off) red[t] += red[t + off];
            __syncthreads();
        }
        if (t == 0) kls[l] = (float)red[0];
        __syncthreads();
    }
    if (t == 0) {
        float cv = 0.f, u = 0.f;
        for (int l = 0; l < 3; ++l) {
            const float m = (float)(commit[l] * (1.0 / 16777216.0));
            cv = __fadd_rn(cv, m);                      // + mean((sg(r)-q)^2)
            cv = __fadd_rn(cv, __fmul_rn(0.25f, m));    // + BETA * mean((r-sg(q))^2)
            u = __fadd_rn(u, __fmul_rn(1e-3f, kls[l]));
        }
        out[SCAL_OFF]     = cv;
        out[SCAL_OFF + 1] = u;
    }
}

__global__ __launch_bounds__(256) void gather_kernel(const float* __restrict__ W,
                                                     float* __restrict__ out) {
    const size_t g = (size_t)blockIdx.x * 256 + threadIdx.x;   // f4 index
    const size_t n = g >> 5;
    const int f = (int)(g & 31);
    const float* codes = out + CODE_OFF + n * 3;
    const int c0 = (int)codes[0], c1 = (int)codes[1], c2 = (int)codes[2];
    const float4 a = *(const float4*)(W + (size_t)c0 * DIMS + 4 * f);
    const float4 b = *(const float4*)(W + (size_t)(KCODES + c1) * DIMS + 4 * f);
    const float4 c = *(const float4*)(W + (size_t)(2 * KCODES + c2) * DIMS + 4 * f);
    float4 o;   // ((q1 + q2) + q3), fp32 like reference
    o.x = __fadd_rn(__fadd_rn(a.x, b.x), c.x);
    o.y = __fadd_rn(__fadd_rn(a.y, b.y), c.y);
    o.z = __fadd_rn(__fadd_rn(a.z, b.z), c.z);
    o.w = __fadd_rn(__fadd_rn(a.w, b.w), c.w);
    *(float4*)(out + n * DIMS + 4 * f) = o;
}

extern "C" void kernel_launch(void* const* d_in, const int* in_sizes, int n_in,
                              void* d_out, int out_size, void* d_ws, size_t ws_size,
                              hipStream_t stream) {
    const float* x = (const float*)d_in[0];
    const float* W = (const float*)d_in[1];
    float* out = (float*)d_out;
    float*  avgp   = (float*)d_ws;
    double* commit = (double*)((char*)d_ws + WS_COMMIT_OFF);
    float*  wkp    = (float*)((char*)d_ws + WS_WK_OFF);
    float*  WT     = (float*)((char*)d_ws + WS_WT_OFF);

    hipLaunchKernelGGL(init_acc, dim3(1), dim3(256), 0, stream, avgp, commit);
    hipLaunchKernelGGL(wnorm_kernel, dim3(768), dim3(256), 0, stream, W, wkp);
    hipLaunchKernelGGL(transpose_w, dim3(16, 4, 3), dim3(256), 0, stream, W, WT);
    for (int l = 0; l < NLEV; ++l)
        hipLaunchKernelGGL(rvq_level, dim3(NROWS / 16), dim3(256), 0, stream,
                           x, W, WT, wkp, out, avgp, commit, l);
    hipLaunchKernelGGL(finalize_kernel, dim3(1), dim3(256), 0, stream, avgp, commit, out);
    hipLaunchKernelGGL(gather_kernel, dim3((NROWS * 32) / 256), dim3(256), 0, stream, W, out);
}

// Round 4
// 3056.732 us; speedup vs baseline: 1.4285x; 1.1653x over previous
//
#include <hip/hip_runtime.h>

// ResidualVectorQuantizer: N=131072, DIM=128, LEVELS=3, K=1024, BETA=0.25, USAGE_REG=1e-3
// Outputs (flat fp32 in d_out): quantized [N*128] | codes [N*3] | commit | usage
//
// Numerics contract with the np fp32 reference (validated in rounds 2-3 — do not change):
//  - m = x·W_k: strict sequential fmaf chain over k=0..127, single accumulator.
//  - d = (S - 2*m) + w via __fsub_rn/__fmul_rn/__fadd_rn (no contraction).
//  - argmin: first occurrence on ties (lexicographic (value, index) min).
//  - residual chain (x - q0) - q1 elementwise fp32, recomputed from codes per level.
//  - losses: tolerance loose (~2%); commit = sum of d at argmin; avgp fp32; KL f64.
//
// Round 4: round 3 spilled acc/wv to scratch (WRITE_SIZE 1.35 GB, VGPR=84 < the
// 96-reg declared tile) because float4 casts into private float arrays defeated
// SROA. This version keeps the identical loop structure but uses native float4
// values (member access only) and __launch_bounds__(256,2) so the register
// allocator can hold the true ~120-reg working set.

#define NROWS   131072
#define DIMS    128
#define KCODES  1024
#define NLEV    3

#define QF_OFF   ((size_t)NROWS * DIMS)          // 16777216
#define CODE_OFF QF_OFF
#define SCAL_OFF (QF_OFF + (size_t)NROWS * 3)    // 17170432

// ---------------- ws layout ----------------
// avgp   : 3*1024 floats  @ 0        (12288 B)
// commit : 3 doubles      @ 12288    (24 B)
// wk     : 3*1024 floats  @ 12320    (12288 B)
// WT     : 3*128*1024 fl  @ 24608    (1572864 B)  k-major codebooks
#define WS_COMMIT_OFF 12288
#define WS_WK_OFF     12320
#define WS_WT_OFF     24608

__global__ __launch_bounds__(256) void init_acc(float* avgp, double* commit) {
    for (int i = threadIdx.x; i < 3072; i += 256) avgp[i] = 0.0f;
    if (threadIdx.x < 3) commit[threadIdx.x] = 0.0;
}

__global__ __launch_bounds__(256) void wnorm_kernel(const float* __restrict__ W,
                                                    float* __restrict__ wk) {
    const int wave = threadIdx.x >> 6, lane = threadIdx.x & 63;
    const int c = blockIdx.x * 4 + wave;          // 0..3071 (level*1024 + k)
    const float2 v = *(const float2*)(W + (size_t)c * DIMS + 2 * lane);
    float s = v.x * v.x + v.y * v.y;
#pragma unroll
    for (int m = 32; m >= 1; m >>= 1) s += __shfl_xor(s, m, 64);
    if (lane == 0) wk[c] = s;
}

// WT[l][k][c] = W[l][c][k]
__global__ __launch_bounds__(256) void transpose_w(const float* __restrict__ W,
                                                   float* __restrict__ WT) {
    __shared__ float tile[32][65];
    const int l = blockIdx.z, k0 = blockIdx.y * 32, c0 = blockIdx.x * 64;
    const float* Wl = W + (size_t)l * KCODES * DIMS;
    float* WTl = WT + (size_t)l * DIMS * KCODES;
    {
        const int ci = threadIdx.x >> 2;            // 0..63
        const int kg = (threadIdx.x & 3) * 8;       // 0,8,16,24
        const float4 a = *(const float4*)(Wl + (size_t)(c0 + ci) * DIMS + k0 + kg);
        const float4 b = *(const float4*)(Wl + (size_t)(c0 + ci) * DIMS + k0 + kg + 4);
        tile[kg + 0][ci] = a.x; tile[kg + 1][ci] = a.y;
        tile[kg + 2][ci] = a.z; tile[kg + 3][ci] = a.w;
        tile[kg + 4][ci] = b.x; tile[kg + 5][ci] = b.y;
        tile[kg + 6][ci] = b.z; tile[kg + 7][ci] = b.w;
    }
    __syncthreads();
    {
        const int k = threadIdx.x >> 3;             // 0..31
        const int cg = (threadIdx.x & 7) * 8;       // 0..56
        float4 o0, o1;
        o0.x = tile[k][cg + 0]; o0.y = tile[k][cg + 1];
        o0.z = tile[k][cg + 2]; o0.w = tile[k][cg + 3];
        o1.x = tile[k][cg + 4]; o1.y = tile[k][cg + 5];
        o1.z = tile[k][cg + 6]; o1.w = tile[k][cg + 7];
        *(float4*)(WTl + (size_t)(k0 + k) * KCODES + c0 + cg)     = o0;
        *(float4*)(WTl + (size_t)(k0 + k) * KCODES + c0 + cg + 4) = o1;
    }
}

#define FMA4(A, rs, wv)                                                        \
    A.x = fmaf(rs, wv.x, A.x); A.y = fmaf(rs, wv.y, A.y);                      \
    A.z = fmaf(rs, wv.z, A.z); A.w = fmaf(rs, wv.w, A.w);

__global__ __launch_bounds__(256, 2) void rvq_level(
    const float* __restrict__ x, const float* __restrict__ W,
    const float* __restrict__ WT, const float* __restrict__ wk,
    float* __restrict__ out, float* __restrict__ avgp,
    double* __restrict__ commit, const int level) {

    __shared__ float rowR[16][132];   // residual rows, row-major (+pad; bcast-read)
    __shared__ float redf[16][17];
    __shared__ float Srow[16];
    __shared__ float wminv[16][4];    // per-wave (row) argmin partials
    __shared__ int   wmini[16][4];
    __shared__ float rowmin[16];
    __shared__ float wsum[16][4];
    __shared__ float rcpL[16];

    const int t = threadIdx.x;
    const int wave = t >> 6, lane = t & 63;
    const int c = wave * 256 + lane * 4;          // this thread's 4 codes
    const size_t base = (size_t)blockIdx.x * 16;
    const float* codesF = out + CODE_OFF;
    const float* WTl = WT + (size_t)level * DIMS * KCODES;
    const float* wkl = wk + level * KCODES;

    // ---- phase 0: stage 16 residual rows into LDS (bit-exact chain from codes) ----
    {
        const int r = t >> 4, i = t & 15;
        const size_t n = base + r;
        float4 v0 = *(const float4*)(x + n * DIMS + i * 8);
        float4 v1 = *(const float4*)(x + n * DIMS + i * 8 + 4);
        for (int j = 0; j < level; ++j) {
            const int idx = (int)codesF[n * 3 + j];
            const float* q = W + ((size_t)(j * KCODES + idx)) * DIMS + i * 8;
            const float4 q0 = *(const float4*)q;
            const float4 q1 = *(const float4*)(q + 4);
            v0.x = __fsub_rn(v0.x, q0.x); v0.y = __fsub_rn(v0.y, q0.y);
            v0.z = __fsub_rn(v0.z, q0.z); v0.w = __fsub_rn(v0.w, q0.w);
            v1.x = __fsub_rn(v1.x, q1.x); v1.y = __fsub_rn(v1.y, q1.y);
            v1.z = __fsub_rn(v1.z, q1.z); v1.w = __fsub_rn(v1.w, q1.w);
        }
        *(float4*)&rowR[r][i * 8]     = v0;
        *(float4*)&rowR[r][i * 8 + 4] = v1;
        float sq = v0.x * v0.x + v0.y * v0.y + v0.z * v0.z + v0.w * v0.w
                 + v1.x * v1.x + v1.y * v1.y + v1.z * v1.z + v1.w * v1.w;
        redf[r][i] = sq;
    }
    __syncthreads();
    if (t < 16) {
        float s = 0.f;
        for (int i = 0; i < 16; ++i) s += redf[t][i];
        Srow[t] = s;   // on-grid shift: order can't affect argmin/softmax
    }
    __syncthreads();

    // ---- phase 1: acc[r] = row_r · W_{c..c+3}, strict k-ascending fmaf chains ----
    float4 acc[16];
#pragma unroll
    for (int r = 0; r < 16; ++r) { acc[r].x = 0.f; acc[r].y = 0.f; acc[r].z = 0.f; acc[r].w = 0.f; }

#pragma unroll 1
    for (int kt = 0; kt < 16; ++kt) {
        const float* wp = WTl + (size_t)(kt * 8) * KCODES + c;
        const float4 wv0 = *(const float4*)(wp + 0 * KCODES);
        const float4 wv1 = *(const float4*)(wp + 1 * KCODES);
        const float4 wv2 = *(const float4*)(wp + 2 * KCODES);
        const float4 wv3 = *(const float4*)(wp + 3 * KCODES);
        const float4 wv4 = *(const float4*)(wp + 4 * KCODES);
        const float4 wv5 = *(const float4*)(wp + 5 * KCODES);
        const float4 wv6 = *(const float4*)(wp + 6 * KCODES);
        const float4 wv7 = *(const float4*)(wp + 7 * KCODES);
#pragma unroll
        for (int r = 0; r < 16; ++r) {
            const float4 ra = *(const float4*)&rowR[r][kt * 8];      // uniform bcast
            const float4 rb = *(const float4*)&rowR[r][kt * 8 + 4];  // uniform bcast
            float4 A = acc[r];
            FMA4(A, ra.x, wv0); FMA4(A, ra.y, wv1);
            FMA4(A, ra.z, wv2); FMA4(A, ra.w, wv3);
            FMA4(A, rb.x, wv4); FMA4(A, rb.y, wv5);
            FMA4(A, rb.z, wv6); FMA4(A, rb.w, wv7);
            acc[r] = A;
        }
    }

    // ---- phase 2: d in place, per-row argmin via lexicographic shuffle reduce ----
    const float4 wkv = *(const float4*)(wkl + c);
#pragma unroll
    for (int r = 0; r < 16; ++r) {
        const float Sr = Srow[r];
        float4 A = acc[r];
        A.x = __fadd_rn(__fsub_rn(Sr, __fmul_rn(2.0f, A.x)), wkv.x);
        A.y = __fadd_rn(__fsub_rn(Sr, __fmul_rn(2.0f, A.y)), wkv.y);
        A.z = __fadd_rn(__fsub_rn(Sr, __fmul_rn(2.0f, A.z)), wkv.z);
        A.w = __fadd_rn(__fsub_rn(Sr, __fmul_rn(2.0f, A.w)), wkv.w);
        acc[r] = A;
        float v = A.x; int bi = c;
        if (A.y < v) { v = A.y; bi = c + 1; }
        if (A.z < v) { v = A.z; bi = c + 2; }
        if (A.w < v) { v = A.w; bi = c + 3; }
#pragma unroll
        for (int m = 1; m < 64; m <<= 1) {
            const float vo = __shfl_xor(v, m, 64);
            const int   io = __shfl_xor(bi, m, 64);
            if (vo < v || (vo == v && io < bi)) { v = vo; bi = io; }
        }
        if (lane == 0) { wminv[r][wave] = v; wmini[r][wave] = bi; }
    }
    __syncthreads();
    if (t < 16) {
        float v = wminv[t][0]; int bi = wmini[t][0];
        for (int w = 1; w < 4; ++w) {
            const float vo = wminv[t][w]; const int io = wmini[t][w];
            if (vo < v || (vo == v && io < bi)) { v = vo; bi = io; }
        }
        rowmin[t] = v;
        out[CODE_OFF + (base + t) * 3 + level] = (float)bi;
    }
    __syncthreads();

    // ---- phase 3: e = exp(dmin - d) in place, row sums via shuffle ----
#pragma unroll
    for (int r = 0; r < 16; ++r) {
        const float mn = rowmin[r];
        float4 A = acc[r];
        A.x = expf(__fsub_rn(mn, A.x));
        A.y = expf(__fsub_rn(mn, A.y));
        A.z = expf(__fsub_rn(mn, A.z));
        A.w = expf(__fsub_rn(mn, A.w));
        acc[r] = A;
        float s = (A.x + A.y) + (A.z + A.w);
#pragma unroll
        for (int m = 1; m < 64; m <<= 1) s += __shfl_xor(s, m, 64);
        if (lane == 0) wsum[r][wave] = s;
    }
    __syncthreads();
    if (t < 16) {
        const float L = (wsum[t][0] + wsum[t][1]) + (wsum[t][2] + wsum[t][3]);
        rcpL[t] = 1.0f / L;
    }
    if (t == 64) {   // commit partial: d at argmin == ||r - q||^2 (loss tolerance loose)
        double cs = 0.0;
        for (int r = 0; r < 16; ++r) cs += (double)rowmin[r];
        atomicAdd(&commit[level], cs);
    }
    __syncthreads();

    // ---- phase 4: avg_probs partials (fp32 atomics, one per code per block) ----
    {
        float s0 = 0.f, s1 = 0.f, s2 = 0.f, s3 = 0.f;
#pragma unroll
        for (int r = 0; r < 16; ++r) {
            const float rl = rcpL[r];
            s0 = fmaf(acc[r].x, rl, s0);
            s1 = fmaf(acc[r].y, rl, s1);
            s2 = fmaf(acc[r].z, rl, s2);
            s3 = fmaf(acc[r].w, rl, s3);
        }
        atomicAdd(&avgp[level * KCODES + c + 0], s0);
        atomicAdd(&avgp[level * KCODES + c + 1], s1);
        atomicAdd(&avgp[level * KCODES + c + 2], s2);
        atomicAdd(&avgp[level * KCODES + c + 3], s3);
    }
}

__global__ __launch_bounds__(256) void finalize_kernel(const float* __restrict__ avgp,
                                                       const double* __restrict__ commit,
                                                       float* __restrict__ out) {
    __shared__ double red[256];
    __shared__ float  kls[3];
    const int t = threadIdx.x;
    for (int l = 0; l < 3; ++l) {
        double p = 0.0;
        for (int k = t; k < KCODES; k += 256) {
            const float avg = avgp[l * KCODES + k] * (1.0f / 131072.0f);
            p += (double)avg * log((double)avg * 1024.0 + 1e-8);
        }
        red[t] = p; __syncthreads();
        for (int off = 128; off >= 1; off >>= 1) {
            if (t < off) red[t] += red[t + off];
            __syncthreads();
        }
        if (t == 0) kls[l] = (float)red[0];
        __syncthreads();
    }
    if (t == 0) {
        float cv = 0.f, u = 0.f;
        for (int l = 0; l < 3; ++l) {
            const float m = (float)(commit[l] * (1.0 / 16777216.0));
            cv = __fadd_rn(cv, m);                      // + mean((sg(r)-q)^2)
            cv = __fadd_rn(cv, __fmul_rn(0.25f, m));    // + BETA * mean((r-sg(q))^2)
            u = __fadd_rn(u, __fmul_rn(1e-3f, kls[l]));
        }
        out[SCAL_OFF]     = cv;
        out[SCAL_OFF + 1] = u;
    }
}

__global__ __launch_bounds__(256) void gather_kernel(const float* __restrict__ W,
                                                     float* __restrict__ out) {
    const size_t g = (size_t)blockIdx.x * 256 + threadIdx.x;   // f4 index
    const size_t n = g >> 5;
    const int f = (int)(g & 31);
    const float* codes = out + CODE_OFF + n * 3;
    const int c0 = (int)codes[0], c1 = (int)codes[1], c2 = (int)codes[2];
    const float4 a = *(const float4*)(W + (size_t)c0 * DIMS + 4 * f);
    const float4 b = *(const float4*)(W + (size_t)(KCODES + c1) * DIMS + 4 * f);
    const float4 c = *(const float4*)(W + (size_t)(2 * KCODES + c2) * DIMS + 4 * f);
    float4 o;   // ((q1 + q2) + q3), fp32 like reference
    o.x = __fadd_rn(__fadd_rn(a.x, b.x), c.x);
    o.y = __fadd_rn(__fadd_rn(a.y, b.y), c.y);
    o.z = __fadd_rn(__fadd_rn(a.z, b.z), c.z);
    o.w = __fadd_rn(__fadd_rn(a.w, b.w), c.w);
    *(float4*)(out + n * DIMS + 4 * f) = o;
}

extern "C" void kernel_launch(void* const* d_in, const int* in_sizes, int n_in,
                              void* d_out, int out_size, void* d_ws, size_t ws_size,
                              hipStream_t stream) {
    const float* x = (const float*)d_in[0];
    const float* W = (const float*)d_in[1];
    float* out = (float*)d_out;
    float*  avgp   = (float*)d_ws;
    double* commit = (double*)((char*)d_ws + WS_COMMIT_OFF);
    float*  wkp    = (float*)((char*)d_ws + WS_WK_OFF);
    float*  WT     = (float*)((char*)d_ws + WS_WT_OFF);

    hipLaunchKernelGGL(init_acc, dim3(1), dim3(256), 0, stream, avgp, commit);
    hipLaunchKernelGGL(wnorm_kernel, dim3(768), dim3(256), 0, stream, W, wkp);
    hipLaunchKernelGGL(transpose_w, dim3(16, 4, 3), dim3(256), 0, stream, W, WT);
    for (int l = 0; l < NLEV; ++l)
        hipLaunchKernelGGL(rvq_level, dim3(NROWS / 16), dim3(256), 0, stream,
                           x, W, WT, wkp, out, avgp, commit, l);
    hipLaunchKernelGGL(finalize_kernel, dim3(1), dim3(256), 0, stream, avgp, commit, out);
    hipLaunchKernelGGL(gather_kernel, dim3((NROWS * 32) / 256), dim3(256), 0, stream, W, out);
}

// Round 5
// 3036.066 us; speedup vs baseline: 1.4382x; 1.0068x over previous
//
#include <hip/hip_runtime.h>

// ResidualVectorQuantizer: N=131072, DIM=128, LEVELS=3, K=1024, BETA=0.25, USAGE_REG=1e-3
// Outputs (flat fp32 in d_out): quantized [N*128] | codes [N*3] | commit | usage
//
// Numerics contract with the np fp32 reference (validated in rounds 2-4 — do not change):
//  - m = x·W_k: strict sequential fmaf chain over k=0..127, single accumulator.
//  - d = (S - 2*m) + w via __fsub_rn/__fmul_rn/__fadd_rn (no contraction).
//  - argmin: first occurrence on ties (lexicographic (value, index) min).
//  - residual chain (x - q0) - q1 elementwise fp32, recomputed from codes per level.
//  - losses: tolerance loose (~2%); commit = sum of d at argmin; avgp fp32; KL f64.
//
// Round 5: round 4 still spilled ~16 floats/thread (WRITE_SIZE 133 MB vs ~35 MB
// legit; VGPR=92 vs ~115 true demand — RA targeted the 96-reg/5-wave granule and
// spilled the excess into the hot loop). Fix: split each kt into two 4-load
// k-halves so the live set is acc(64)+wv(16)+ra(4)+addr ~ 94 regs (fits 96), and
// launch_bounds(256,1) so any extra pressure allocates instead of spilling.

#define NROWS   131072
#define DIMS    128
#define KCODES  1024
#define NLEV    3

#define QF_OFF   ((size_t)NROWS * DIMS)          // 16777216
#define CODE_OFF QF_OFF
#define SCAL_OFF (QF_OFF + (size_t)NROWS * 3)    // 17170432

// ---------------- ws layout ----------------
// avgp   : 3*1024 floats  @ 0        (12288 B)
// commit : 3 doubles      @ 12288    (24 B)
// wk     : 3*1024 floats  @ 12320    (12288 B)
// WT     : 3*128*1024 fl  @ 24608    (1572864 B)  k-major codebooks
#define WS_COMMIT_OFF 12288
#define WS_WK_OFF     12320
#define WS_WT_OFF     24608

__global__ __launch_bounds__(256) void init_acc(float* avgp, double* commit) {
    for (int i = threadIdx.x; i < 3072; i += 256) avgp[i] = 0.0f;
    if (threadIdx.x < 3) commit[threadIdx.x] = 0.0;
}

__global__ __launch_bounds__(256) void wnorm_kernel(const float* __restrict__ W,
                                                    float* __restrict__ wk) {
    const int wave = threadIdx.x >> 6, lane = threadIdx.x & 63;
    const int c = blockIdx.x * 4 + wave;          // 0..3071 (level*1024 + k)
    const float2 v = *(const float2*)(W + (size_t)c * DIMS + 2 * lane);
    float s = v.x * v.x + v.y * v.y;
#pragma unroll
    for (int m = 32; m >= 1; m >>= 1) s += __shfl_xor(s, m, 64);
    if (lane == 0) wk[c] = s;
}

// WT[l][k][c] = W[l][c][k]
__global__ __launch_bounds__(256) void transpose_w(const float* __restrict__ W,
                                                   float* __restrict__ WT) {
    __shared__ float tile[32][65];
    const int l = blockIdx.z, k0 = blockIdx.y * 32, c0 = blockIdx.x * 64;
    const float* Wl = W + (size_t)l * KCODES * DIMS;
    float* WTl = WT + (size_t)l * DIMS * KCODES;
    {
        const int ci = threadIdx.x >> 2;            // 0..63
        const int kg = (threadIdx.x & 3) * 8;       // 0,8,16,24
        const float4 a = *(const float4*)(Wl + (size_t)(c0 + ci) * DIMS + k0 + kg);
        const float4 b = *(const float4*)(Wl + (size_t)(c0 + ci) * DIMS + k0 + kg + 4);
        tile[kg + 0][ci] = a.x; tile[kg + 1][ci] = a.y;
        tile[kg + 2][ci] = a.z; tile[kg + 3][ci] = a.w;
        tile[kg + 4][ci] = b.x; tile[kg + 5][ci] = b.y;
        tile[kg + 6][ci] = b.z; tile[kg + 7][ci] = b.w;
    }
    __syncthreads();
    {
        const int k = threadIdx.x >> 3;             // 0..31
        const int cg = (threadIdx.x & 7) * 8;       // 0..56
        float4 o0, o1;
        o0.x = tile[k][cg + 0]; o0.y = tile[k][cg + 1];
        o0.z = tile[k][cg + 2]; o0.w = tile[k][cg + 3];
        o1.x = tile[k][cg + 4]; o1.y = tile[k][cg + 5];
        o1.z = tile[k][cg + 6]; o1.w = tile[k][cg + 7];
        *(float4*)(WTl + (size_t)(k0 + k) * KCODES + c0 + cg)     = o0;
        *(float4*)(WTl + (size_t)(k0 + k) * KCODES + c0 + cg + 4) = o1;
    }
}

#define FMA4(A, rs, wv)                                                        \
    A.x = fmaf(rs, wv.x, A.x); A.y = fmaf(rs, wv.y, A.y);                      \
    A.z = fmaf(rs, wv.z, A.z); A.w = fmaf(rs, wv.w, A.w);

__global__ __launch_bounds__(256, 1) void rvq_level(
    const float* __restrict__ x, const float* __restrict__ W,
    const float* __restrict__ WT, const float* __restrict__ wk,
    float* __restrict__ out, float* __restrict__ avgp,
    double* __restrict__ commit, const int level) {

    __shared__ float rowR[16][132];   // residual rows, row-major (+pad; bcast-read)
    __shared__ float redf[16][17];
    __shared__ float Srow[16];
    __shared__ float wminv[16][4];    // per-wave (row) argmin partials
    __shared__ int   wmini[16][4];
    __shared__ float rowmin[16];
    __shared__ float wsum[16][4];
    __shared__ float rcpL[16];

    const int t = threadIdx.x;
    const int wave = t >> 6, lane = t & 63;
    const int c = wave * 256 + lane * 4;          // this thread's 4 codes
    const size_t base = (size_t)blockIdx.x * 16;
    const float* codesF = out + CODE_OFF;
    const float* WTl = WT + (size_t)level * DIMS * KCODES;
    const float* wkl = wk + level * KCODES;

    // ---- phase 0: stage 16 residual rows into LDS (bit-exact chain from codes) ----
    {
        const int r = t >> 4, i = t & 15;
        const size_t n = base + r;
        float4 v0 = *(const float4*)(x + n * DIMS + i * 8);
        float4 v1 = *(const float4*)(x + n * DIMS + i * 8 + 4);
        for (int j = 0; j < level; ++j) {
            const int idx = (int)codesF[n * 3 + j];
            const float* q = W + ((size_t)(j * KCODES + idx)) * DIMS + i * 8;
            const float4 q0 = *(const float4*)q;
            const float4 q1 = *(const float4*)(q + 4);
            v0.x = __fsub_rn(v0.x, q0.x); v0.y = __fsub_rn(v0.y, q0.y);
            v0.z = __fsub_rn(v0.z, q0.z); v0.w = __fsub_rn(v0.w, q0.w);
            v1.x = __fsub_rn(v1.x, q1.x); v1.y = __fsub_rn(v1.y, q1.y);
            v1.z = __fsub_rn(v1.z, q1.z); v1.w = __fsub_rn(v1.w, q1.w);
        }
        *(float4*)&rowR[r][i * 8]     = v0;
        *(float4*)&rowR[r][i * 8 + 4] = v1;
        float sq = v0.x * v0.x + v0.y * v0.y + v0.z * v0.z + v0.w * v0.w
                 + v1.x * v1.x + v1.y * v1.y + v1.z * v1.z + v1.w * v1.w;
        redf[r][i] = sq;
    }
    __syncthreads();
    if (t < 16) {
        float s = 0.f;
        for (int i = 0; i < 16; ++i) s += redf[t][i];
        Srow[t] = s;   // on-grid shift: order can't affect argmin/softmax
    }
    __syncthreads();

    // ---- phase 1: acc[r] = row_r · W_{c..c+3}, strict k-ascending fmaf chains ----
    // kt split into two 4-load halves to keep live VGPRs ~94 (acc 64 + wv 16 + ra 4):
    // fits the 96-reg/5-wave allocation granule with no scratch spill.
    float4 acc[16];
#pragma unroll
    for (int r = 0; r < 16; ++r) { acc[r].x = 0.f; acc[r].y = 0.f; acc[r].z = 0.f; acc[r].w = 0.f; }

#pragma unroll 1
    for (int kt = 0; kt < 16; ++kt) {
        const float* wp = WTl + (size_t)(kt * 8) * KCODES + c;
        {   // half 0: k = kt*8 .. kt*8+3
            const float4 wv0 = *(const float4*)(wp + 0 * KCODES);
            const float4 wv1 = *(const float4*)(wp + 1 * KCODES);
            const float4 wv2 = *(const float4*)(wp + 2 * KCODES);
            const float4 wv3 = *(const float4*)(wp + 3 * KCODES);
#pragma unroll
            for (int r = 0; r < 16; ++r) {
                const float4 ra = *(const float4*)&rowR[r][kt * 8];      // bcast
                float4 A = acc[r];
                FMA4(A, ra.x, wv0); FMA4(A, ra.y, wv1);
                FMA4(A, ra.z, wv2); FMA4(A, ra.w, wv3);
                acc[r] = A;
            }
        }
        {   // half 1: k = kt*8+4 .. kt*8+7
            const float4 wv4 = *(const float4*)(wp + 4 * KCODES);
            const float4 wv5 = *(const float4*)(wp + 5 * KCODES);
            const float4 wv6 = *(const float4*)(wp + 6 * KCODES);
            const float4 wv7 = *(const float4*)(wp + 7 * KCODES);
#pragma unroll
            for (int r = 0; r < 16; ++r) {
                const float4 rb = *(const float4*)&rowR[r][kt * 8 + 4];  // bcast
                float4 A = acc[r];
                FMA4(A, rb.x, wv4); FMA4(A, rb.y, wv5);
                FMA4(A, rb.z, wv6); FMA4(A, rb.w, wv7);
                acc[r] = A;
            }
        }
    }

    // ---- phase 2: d in place, per-row argmin via lexicographic shuffle reduce ----
    const float4 wkv = *(const float4*)(wkl + c);
#pragma unroll
    for (int r = 0; r < 16; ++r) {
        const float Sr = Srow[r];
        float4 A = acc[r];
        A.x = __fadd_rn(__fsub_rn(Sr, __fmul_rn(2.0f, A.x)), wkv.x);
        A.y = __fadd_rn(__fsub_rn(Sr, __fmul_rn(2.0f, A.y)), wkv.y);
        A.z = __fadd_rn(__fsub_rn(Sr, __fmul_rn(2.0f, A.z)), wkv.z);
        A.w = __fadd_rn(__fsub_rn(Sr, __fmul_rn(2.0f, A.w)), wkv.w);
        acc[r] = A;
        float v = A.x; int bi = c;
        if (A.y < v) { v = A.y; bi = c + 1; }
        if (A.z < v) { v = A.z; bi = c + 2; }
        if (A.w < v) { v = A.w; bi = c + 3; }
#pragma unroll
        for (int m = 1; m < 64; m <<= 1) {
            const float vo = __shfl_xor(v, m, 64);
            const int   io = __shfl_xor(bi, m, 64);
            if (vo < v || (vo == v && io < bi)) { v = vo; bi = io; }
        }
        if (lane == 0) { wminv[r][wave] = v; wmini[r][wave] = bi; }
    }
    __syncthreads();
    if (t < 16) {
        float v = wminv[t][0]; int bi = wmini[t][0];
        for (int w = 1; w < 4; ++w) {
            const float vo = wminv[t][w]; const int io = wmini[t][w];
            if (vo < v || (vo == v && io < bi)) { v = vo; bi = io; }
        }
        rowmin[t] = v;
        out[CODE_OFF + (base + t) * 3 + level] = (float)bi;
    }
    __syncthreads();

    // ---- phase 3: e = exp(dmin - d) in place, row sums via shuffle ----
#pragma unroll
    for (int r = 0; r < 16; ++r) {
        const float mn = rowmin[r];
        float4 A = acc[r];
        A.x = expf(__fsub_rn(mn, A.x));
        A.y = expf(__fsub_rn(mn, A.y));
        A.z = expf(__fsub_rn(mn, A.z));
        A.w = expf(__fsub_rn(mn, A.w));
        acc[r] = A;
        float s = (A.x + A.y) + (A.z + A.w);
#pragma unroll
        for (int m = 1; m < 64; m <<= 1) s += __shfl_xor(s, m, 64);
        if (lane == 0) wsum[r][wave] = s;
    }
    __syncthreads();
    if (t < 16) {
        const float L = (wsum[t][0] + wsum[t][1]) + (wsum[t][2] + wsum[t][3]);
        rcpL[t] = 1.0f / L;
    }
    if (t == 64) {   // commit partial: d at argmin == ||r - q||^2 (loss tolerance loose)
        double cs = 0.0;
        for (int r = 0; r < 16; ++r) cs += (double)rowmin[r];
        atomicAdd(&commit[level], cs);
    }
    __syncthreads();

    // ---- phase 4: avg_probs partials (fp32 atomics, one per code per block) ----
    {
        float s0 = 0.f, s1 = 0.f, s2 = 0.f, s3 = 0.f;
#pragma unroll
        for (int r = 0; r < 16; ++r) {
            const float rl = rcpL[r];
            s0 = fmaf(acc[r].x, rl, s0);
            s1 = fmaf(acc[r].y, rl, s1);
            s2 = fmaf(acc[r].z, rl, s2);
            s3 = fmaf(acc[r].w, rl, s3);
        }
        atomicAdd(&avgp[level * KCODES + c + 0], s0);
        atomicAdd(&avgp[level * KCODES + c + 1], s1);
        atomicAdd(&avgp[level * KCODES + c + 2], s2);
        atomicAdd(&avgp[level * KCODES + c + 3], s3);
    }
}

__global__ __launch_bounds__(256) void finalize_kernel(const float* __restrict__ avgp,
                                                       const double* __restrict__ commit,
                                                       float* __restrict__ out) {
    __shared__ double red[256];
    __shared__ float  kls[3];
    const int t = threadIdx.x;
    for (int l = 0; l < 3; ++l) {
        double p = 0.0;
        for (int k = t; k < KCODES; k += 256) {
            const float avg = avgp[l * KCODES + k] * (1.0f / 131072.0f);
            p += (double)avg * log((double)avg * 1024.0 + 1e-8);
        }
        red[t] = p; __syncthreads();
        for (int off = 128; off >= 1; off >>= 1) {
            if (t < off) red[t] += red[t + off];
            __syncthreads();
        }
        if (t == 0) kls[l] = (float)red[0];
        __syncthreads();
    }
    if (t == 0) {
        float cv = 0.f, u = 0.f;
        for (int l = 0; l < 3; ++l) {
            const float m = (float)(commit[l] * (1.0 / 16777216.0));
            cv = __fadd_rn(cv, m);                      // + mean((sg(r)-q)^2)
            cv = __fadd_rn(cv, __fmul_rn(0.25f, m));    // + BETA * mean((r-sg(q))^2)
            u = __fadd_rn(u, __fmul_rn(1e-3f, kls[l]));
        }
        out[SCAL_OFF]     = cv;
        out[SCAL_OFF + 1] = u;
    }
}

__global__ __launch_bounds__(256) void gather_kernel(const float* __restrict__ W,
                                                     float* __restrict__ out) {
    const size_t g = (size_t)blockIdx.x * 256 + threadIdx.x;   // f4 index
    const size_t n = g >> 5;
    const int f = (int)(g & 31);
    const float* codes = out + CODE_OFF + n * 3;
    const int c0 = (int)codes[0], c1 = (int)codes[1], c2 = (int)codes[2];
    const float4 a = *(const float4*)(W + (size_t)c0 * DIMS + 4 * f);
    const float4 b = *(const float4*)(W + (size_t)(KCODES + c1) * DIMS + 4 * f);
    const float4 c = *(const float4*)(W + (size_t)(2 * KCODES + c2) * DIMS + 4 * f);
    float4 o;   // ((q1 + q2) + q3), fp32 like reference
    o.x = __fadd_rn(__fadd_rn(a.x, b.x), c.x);
    o.y = __fadd_rn(__fadd_rn(a.y, b.y), c.y);
    o.z = __fadd_rn(__fadd_rn(a.z, b.z), c.z);
    o.w = __fadd_rn(__fadd_rn(a.w, b.w), c.w);
    *(float4*)(out + n * DIMS + 4 * f) = o;
}

extern "C" void kernel_launch(void* const* d_in, const int* in_sizes, int n_in,
                              void* d_out, int out_size, void* d_ws, size_t ws_size,
                              hipStream_t stream) {
    const float* x = (const float*)d_in[0];
    const float* W = (const float*)d_in[1];
    float* out = (float*)d_out;
    float*  avgp   = (float*)d_ws;
    double* commit = (double*)((char*)d_ws + WS_COMMIT_OFF);
    float*  wkp    = (float*)((char*)d_ws + WS_WK_OFF);
    float*  WT     = (float*)((char*)d_ws + WS_WT_OFF);

    hipLaunchKernelGGL(init_acc, dim3(1), dim3(256), 0, stream, avgp, commit);
    hipLaunchKernelGGL(wnorm_kernel, dim3(768), dim3(256), 0, stream, W, wkp);
    hipLaunchKernelGGL(transpose_w, dim3(16, 4, 3), dim3(256), 0, stream, W, WT);
    for (int l = 0; l < NLEV; ++l)
        hipLaunchKernelGGL(rvq_level, dim3(NROWS / 16), dim3(256), 0, stream,
                           x, W, WT, wkp, out, avgp, commit, l);
    hipLaunchKernelGGL(finalize_kernel, dim3(1), dim3(256), 0, stream, avgp, commit, out);
    hipLaunchKernelGGL(gather_kernel, dim3((NROWS * 32) / 256), dim3(256), 0, stream, W, out);
}